// Round 4
// baseline (237.432 us; speedup 1.0000x reference)
//
#include <hip/hip_runtime.h>

#define NPG    50
#define HF     128
#define FDIM   64
#define NGRAPH 2048
#define EPG    400
#define SP     72     // featT row stride (bf16), 16B-aligned rows, bank-skewed
#define HB     136    // hbuf row stride (bf16), 16B-aligned rows
#define CNTW   16     // cnt row stride in ints (64 byte-counts per row)

typedef __attribute__((ext_vector_type(8))) short bf16x8;
typedef __attribute__((ext_vector_type(4))) float floatx4;
typedef __bf16 bfv2 __attribute__((ext_vector_type(2)));

__device__ __forceinline__ float leaky(float x, float s) { return x >= 0.f ? x : x * s; }

// fp32->bf16 RNE via native __bf16 cast (gfx950: v_cvt_pk_bf16_f32); packed
// pair = 1 inst for 2 values.
__device__ __forceinline__ unsigned short f2bf(float f) {
    __bf16 b = (__bf16)f;
    unsigned short u;
    __builtin_memcpy(&u, &b, 2);
    return u;
}
__device__ __forceinline__ unsigned f2bfpk(float a, float b) {
    bfv2 v;
    v[0] = (__bf16)a;
    v[1] = (__bf16)b;
    unsigned u;
    __builtin_memcpy(&u, &v, 4);
    return u;
}
__device__ __forceinline__ float bf2f(unsigned short h) {
    return __uint_as_float(((unsigned)h) << 16);
}
__device__ __forceinline__ int fkey(float f) { int b = __float_as_int(f); return b >= 0 ? b : b ^ 0x7fffffff; }
__device__ __forceinline__ float funkey(int k) { return __int_as_float(k >= 0 ? k : k ^ 0x7fffffff); }

// Build transposed bf16 weights with an appended 16-col attention N-tile:
//   wt0[272][64]  = [W0|resW0|attn0]^T   (attn tile rows 256..271)
//   wt1/wt2[144][128] = [W|attn]^T       (attn tile rows 128..143)
// Attn tile local cols: 0..7 = [el_h0_hi, el_h0_lo, el_h1_hi, el_h1_lo,
//                               er_h0_hi, er_h0_lo, er_h1_hi, er_h1_lo]
// (hi/lo bf16 split of W@al / W@ar -> fp32-accurate el/er from one MFMA tile);
// cols 8..15 zero.
// Blocks 0..63: main W transposes.  Blocks 64..83: attn dots, one thread per
// output element (the old single-block serial version was a ~20us one-CU
// tail, R2 post-mortem).
__global__ void prep_w(const float* __restrict__ W0, const float* __restrict__ rW0,
                       const float* __restrict__ W1, const float* __restrict__ W2,
                       const float* __restrict__ al0, const float* __restrict__ ar0,
                       const float* __restrict__ al1, const float* __restrict__ ar1,
                       const float* __restrict__ al2, const float* __restrict__ ar2,
                       unsigned short* __restrict__ wt0, unsigned short* __restrict__ wt1,
                       unsigned short* __restrict__ wt2) {
    if (blockIdx.x >= 64) {
        int gid = (blockIdx.x - 64) * 256 + threadIdx.x;   // [0, 5120)
        int la, k;
        const float* W;
        const float *alp, *arp;
        unsigned short* dstp;
        if (gid < 1024) {            // layer 0 tile: 16 la x 64 k
            la = gid >> 6; k = gid & 63;
            W = W0; alp = al0; arp = ar0;
            dstp = &wt0[(256 + la) * 64 + k];
        } else {
            int q = gid - 1024;      // layers 1/2: 2 x 16 la x 128 k
            int l = q >> 11;
            la = (q >> 7) & 15; k = q & 127;
            W = l ? W2 : W1;
            alp = l ? al2 : al1; arp = l ? ar2 : ar1;
            dstp = &(l ? wt2 : wt1)[(128 + la) * 128 + k];
        }
        unsigned short o = 0;
        if (la < 8) {
            const float* a = (la < 4) ? alp : arp;
            int h = (la >> 1) & 1;
            float v = 0.f;
            for (int f = 0; f < 64; ++f) v += W[k * (2 * FDIM) + h * 64 + f] * a[h * 64 + f];
            __bf16 hi = (__bf16)v;
            if (la & 1) o = f2bf(v - (float)hi);
            else __builtin_memcpy(&o, &hi, 2);
        }
        *dstp = o;
        return;
    }
    int i = blockIdx.x * 256 + threadIdx.x;
    if (i < 256 * 64) {
        int n = i >> 6, k = i & 63;
        float v = (n < 128) ? W0[k * 128 + n] : rW0[k * 128 + (n - 128)];
        wt0[i] = f2bf(v);
    }
    if (i < 128 * 128) {
        int n = i >> 7, k = i & 127;
        wt1[i] = f2bf(W1[k * 128 + n]);
        wt2[i] = f2bf(W2[k * 128 + n]);
    }
}

// One GAT layer, fully in-block.  hbuf holds (RESW: x@resW0, else: input h) on
// entry to the epilogue, and holds this layer's output y on exit.
// NO float atomics: cross-wave float reductions via uniquely-owned LDS slots +
// fixed-order final sums -> bit-deterministic.
// R4 register diet: ks-outer GEMM re-reads the A-fragment from LDS per ks
// (1 live a-frag instead of afr[KS]=16 regs) so the whole kernel fits the
// (512,8) 64-reg cap WITHOUT the catastrophic spill R2 hit (VGPR=32,
// WRITE_SIZE 91 MB).  MFMA order per accumulator unchanged -> bit-identical.
template <int K, bool RESW>
__device__ __forceinline__ void gat_layer(
    const bf16x8* afr_in,                       // RESW: preloaded A-frags
    const unsigned short* __restrict__ Wt,
    const float* __restrict__ gp, const float* __restrict__ bp,
    float* __restrict__ out, int layer, int g, int t,
    unsigned short* featT, unsigned short* hbuf, int* cnt,
    float* el_s, float* er_s, int* elmax_i,
    float* lnp, float* lnq, float* psum4, float* gbL)
{
    const int w = t >> 6, lane = t & 63, quad = lane >> 4, l16 = lane & 15;
    constexpr int KS = K / 32;
    constexpr int ATTN_ROW = RESW ? 256 : 128;  // attn tile base row in Wt
    const int mt = w & 3;
    int mrow = mt * 16 + l16;
    if (mrow >= NPG) mrow = NPG - 1;
    const floatx4 zf = {0.f, 0.f, 0.f, 0.f};

    // per-layer g|b reload (1 KB LDS instead of 3 KB for all layers);
    // written before B1, read after B2 -> ordered; prev layer's reads end
    // before its B3 -> no race.
    if (t < HF) { gbL[t] = gp[t]; gbL[HF + t] = bp[t]; }

    // ---- main GEMM via MFMA + featT/res stores ----
    if constexpr (RESW) {
        // A-frags live in 8 regs (K=64), from global x (hbuf is being
        // WRITTEN during this GEMM -- must not re-read it here).
        // two SEQUENTIAL passes of 4 N-tiles: peak acc = 16 AGPRs.
        // unroll 1 is load-bearing -- full unroll re-fuses to 32 AGPRs.
#pragma unroll 1
        for (int half = 0; half < 2; ++half) {
            const int nb = (w >> 2) * 8 + half * 4;
            floatx4 acc[4];
#pragma unroll
            for (int nt = 0; nt < 4; ++nt) acc[nt] = zf;
#pragma unroll
            for (int ks = 0; ks < KS; ++ks) {
#pragma unroll
                for (int nt = 0; nt < 4; ++nt) {
                    bf16x8 b = *(const bf16x8*)(Wt + (size_t)((nb + nt) * 16 + l16) * K + ks * 32 + quad * 8);
                    acc[nt] = __builtin_amdgcn_mfma_f32_16x16x32_bf16(afr_in[ks], b, acc[nt], 0, 0, 0);
                }
            }
#pragma unroll
            for (int nt = 0; nt < 4; ++nt) {
                int n = (nb + nt) * 16 + l16;
                if (n < HF) {
                    uint2 pk = {f2bfpk(acc[nt][0], acc[nt][1]),
                                f2bfpk(acc[nt][2], acc[nt][3])};
                    *(uint2*)&featT[n * SP + mt * 16 + quad * 4] = pk;
                } else {
#pragma unroll
                    for (int r = 0; r < 4; ++r) {
                        int dr = mt * 16 + quad * 4 + r;
                        if (dr < NPG) hbuf[dr * HB + (n - HF)] = f2bf(acc[nt][r]);
                    }
                }
            }
        }
        // attn tile: A from regs
        if (w < 4) {
            floatx4 ae = zf;
#pragma unroll
            for (int ks = 0; ks < KS; ++ks) {
                bf16x8 b = *(const bf16x8*)(Wt + (size_t)(ATTN_ROW + l16) * K + ks * 32 + quad * 8);
                ae = __builtin_amdgcn_mfma_f32_16x16x32_bf16(afr_in[ks], b, ae, 0, 0, 0);
            }
#pragma unroll
            for (int r = 0; r < 4; ++r) {
                float v = ae[r] + __shfl_xor(ae[r], 1, 64);   // hi + lo
                if ((l16 & 1) == 0 && l16 < 8) {
                    int row = mt * 16 + quad * 4 + r;
                    int hd2 = (l16 >> 1) & 1;
                    if (l16 < 4) {
                        el_s[hd2 * 64 + row] = v;
                        atomicMax(&elmax_i[hd2], fkey(v));    // int max: exact
                    } else {
                        er_s[hd2 * 64 + row] = v;
                    }
                }
            }
        }
    } else {
        // ks-outer: ONE a-frag live (re-read from LDS per ks), 4 b in flight,
        // acc[4] in AGPRs -> ~30-reg GEMM live set.
        const int ntbase = (w >> 2) * 4;
        floatx4 acc[4];
#pragma unroll
        for (int nt = 0; nt < 4; ++nt) acc[nt] = zf;
#pragma unroll
        for (int ks = 0; ks < KS; ++ks) {
            bf16x8 a = *(const bf16x8*)&hbuf[mrow * HB + ks * 32 + quad * 8];
#pragma unroll
            for (int nt = 0; nt < 4; ++nt) {
                bf16x8 b = *(const bf16x8*)(Wt + (size_t)((ntbase + nt) * 16 + l16) * K + ks * 32 + quad * 8);
                acc[nt] = __builtin_amdgcn_mfma_f32_16x16x32_bf16(a, b, acc[nt], 0, 0, 0);
            }
        }
#pragma unroll
        for (int nt = 0; nt < 4; ++nt) {
            int n = (ntbase + nt) * 16 + l16;
            uint2 pk = {f2bfpk(acc[nt][0], acc[nt][1]),
                        f2bfpk(acc[nt][2], acc[nt][3])};
            *(uint2*)&featT[n * SP + mt * 16 + quad * 4] = pk;
        }
        // attn tile: re-read A from hbuf (still valid: y overwrite is post-B2)
        if (w < 4) {
            floatx4 ae = zf;
#pragma unroll
            for (int ks = 0; ks < KS; ++ks) {
                bf16x8 a = *(const bf16x8*)&hbuf[mrow * HB + ks * 32 + quad * 8];
                bf16x8 b = *(const bf16x8*)(Wt + (size_t)(ATTN_ROW + l16) * K + ks * 32 + quad * 8);
                ae = __builtin_amdgcn_mfma_f32_16x16x32_bf16(a, b, ae, 0, 0, 0);
            }
#pragma unroll
            for (int r = 0; r < 4; ++r) {
                float v = ae[r] + __shfl_xor(ae[r], 1, 64);   // hi + lo
                if ((l16 & 1) == 0 && l16 < 8) {
                    int row = mt * 16 + quad * 4 + r;
                    int hd2 = (l16 >> 1) & 1;
                    if (l16 < 4) {
                        el_s[hd2 * 64 + row] = v;
                        atomicMax(&elmax_i[hd2], fkey(v));    // int max: exact
                    } else {
                        er_s[hd2 * 64 + row] = v;
                    }
                }
            }
        }
    }
    __syncthreads();   // B1

    // ---- exp A-frag + aggregation MFMA + epilogue ----
    const int hd = w >> 2, amt = w & 3;
    const int d = amt * 16 + l16;    // A-frag dst row

    // max_s leaky(el+er) = leaky(max_s el + er)  (leaky monotone)
    const float erd = er_s[hd * 64 + d];
    const float md = leaky(funkey(elmax_i[hd]) + erd, 0.2f);
    // rows >= NPG clamp onto row NPG-1's counts: their ag output is garbage
    // but every consumer is dd<NPG-guarded.
    const int dcl = d < NPG ? d : NPG - 1;
    const int* crow = &cnt[dcl * CNTW];

    bf16x8 ap[2];
    float rowsum = 0.f;
#pragma unroll
    for (int ks = 0; ks < 2; ++ks) {
        float4 ev0 = *(const float4*)&el_s[hd * 64 + ks * 32 + quad * 8];
        float4 ev1 = *(const float4*)&el_s[hd * 64 + ks * 32 + quad * 8 + 4];
        const float ev[8] = {ev0.x, ev0.y, ev0.z, ev0.w, ev1.x, ev1.y, ev1.z, ev1.w};
        int2 cw = *(const int2*)&crow[ks * 8 + quad * 2];   // 8 byte-counts
        unsigned au[4];
#pragma unroll
        for (int jp = 0; jp < 4; ++jp) {                // pairs (2*jp, 2*jp+1)
            float e0 = ev[2 * jp] + erd;
            float e1 = ev[2 * jp + 1] + erd;
            e0 = fmaxf(e0, 0.2f * e0);                  // leaky (slope < 1)
            e1 = fmaxf(e1, 0.2f * e1);
            float p0 = __expf(e0 - md);
            float p1 = __expf(e1 - md);
            int w32 = (jp & 2) ? cw.y : cw.x;
            int sh = (jp & 1) * 16;
            int c0 = (w32 >> sh) & 0xff;
            int c1 = (w32 >> (sh + 8)) & 0xff;
            unsigned pk = f2bfpk((float)c0 * p0, (float)c1 * p1);  // c==0 -> exact 0
            au[jp] = pk;
            rowsum += __uint_as_float(pk << 16) + __uint_as_float(pk & 0xffff0000u);
        }
        __builtin_memcpy(&ap[ks], au, 16);
    }
    rowsum += __shfl_xor(rowsum, 16, 64);
    rowsum += __shfl_xor(rowsum, 32, 64);
    const float rden = 1.f / fmaxf(rowsum, 1e-30f);   // every lane holds row d's rden

    floatx4 ag[4];
#pragma unroll
    for (int nt = 0; nt < 4; ++nt) ag[nt] = zf;
#pragma unroll
    for (int ks = 0; ks < 2; ++ks) {
#pragma unroll
        for (int nt = 0; nt < 4; ++nt) {
            bf16x8 b = *(const bf16x8*)&featT[(hd * 64 + nt * 16 + l16) * SP + ks * 32 + quad * 8];
            ag[nt] = __builtin_amdgcn_mfma_f32_16x16x32_bf16(ap[ks], b, ag[nt], 0, 0, 0);
        }
    }

    // scale + residual; LN partials into uniquely-owned slots (deterministic).
    // rden for accumulator row dd lives in lane l16=quad*4+r of this 16-group:
    // one width-16 shfl replaces the old rden_s LDS round-trip.
    float s1[4] = {0,0,0,0}, s2[4] = {0,0,0,0};
#pragma unroll
    for (int r = 0; r < 4; ++r) {
        int dd = amt * 16 + quad * 4 + r;
        float rdv = __shfl(rden, quad * 4 + r, 16);
        int dc = dd < NPG ? dd : NPG - 1;
#pragma unroll
        for (int nt = 0; nt < 4; ++nt) {
            int col = hd * 64 + nt * 16 + l16;
            float vv = fmaf(ag[nt][r], rdv, bf2f(hbuf[dc * HB + col]));
            ag[nt][r] = vv;
            s1[r] += vv;
            s2[r] = fmaf(vv, vv, s2[r]);
        }
    }
#pragma unroll
    for (int m = 1; m <= 8; m <<= 1) {
#pragma unroll
        for (int r = 0; r < 4; ++r) {
            s1[r] += __shfl_xor(s1[r], m, 64);
            s2[r] += __shfl_xor(s2[r], m, 64);
        }
    }
    if (l16 == 0) {
#pragma unroll
        for (int r = 0; r < 4; ++r) {
            int dd = amt * 16 + quad * 4 + r;   // slot [hd][dd]: single writer
            lnp[hd * 64 + dd] = s1[r];
            lnq[hd * 64 + dd] = s2[r];
        }
    }
    __syncthreads();   // B2: LN slots written; hbuf/featT reads done

    // re-arm elmax for the next layer (reads finished at B2, writes after B3)
    if (t < 2) elmax_i[t] = (int)0x80000000;

    // normalize + affine + leaky -> y into hbuf; readout partials from fp32 y
    float part[4] = {0, 0, 0, 0};
#pragma unroll
    for (int r = 0; r < 4; ++r) {
        int dd = amt * 16 + quad * 4 + r;
        if (dd < NPG) {
            float mus = lnp[dd] + lnp[64 + dd];         // fixed order: head0 + head1
            float sqs = lnq[dd] + lnq[64 + dd];
            float mu = mus * (1.f / HF);
            float rs = rsqrtf(sqs * (1.f / HF) - mu * mu + 1e-5f);
            float y4[4];
#pragma unroll
            for (int nt = 0; nt < 4; ++nt) {
                int col = hd * 64 + nt * 16 + l16;
                float y = (ag[nt][r] - mu) * rs * gbL[col] + gbL[HF + col];
                y = leaky(y, 0.1f);
                y4[nt] = y;
                part[nt] += y;
            }
            unsigned pk01 = f2bfpk(y4[0], y4[1]);
            unsigned pk23 = f2bfpk(y4[2], y4[3]);
            int base = dd * HB + hd * 64 + l16;
            hbuf[base]      = (unsigned short)(pk01 & 0xffffu);
            hbuf[base + 16] = (unsigned short)(pk01 >> 16);
            hbuf[base + 32] = (unsigned short)(pk23 & 0xffffu);
            hbuf[base + 48] = (unsigned short)(pk23 >> 16);
        }
    }
    // sum part over quads in-wave; slot [amt][col]: single writer per slot
#pragma unroll
    for (int nt = 0; nt < 4; ++nt) {
        part[nt] += __shfl_xor(part[nt], 16, 64);
        part[nt] += __shfl_xor(part[nt], 32, 64);
    }
    if (quad == 0) {
#pragma unroll
        for (int nt = 0; nt < 4; ++nt)
            psum4[amt * HF + hd * 64 + nt * 16 + l16] = part[nt];
    }
    __syncthreads();   // B3: y visible (next layer A-frags), psum4 complete

    if (t < FDIM) {
        float s = 0.f;
#pragma unroll
        for (int a4 = 0; a4 < 4; ++a4)                   // fixed summation order
            s += psum4[a4 * HF + t] + psum4[a4 * HF + t + FDIM];
        out[(size_t)g * (3 * FDIM) + layer * FDIM + t] = leaky(s * (1.f / (2 * NPG)), 0.1f);
    }
    // no re-zero needed: lnp/lnq/psum4 slots are fully overwritten next layer
}

// One block per graph runs all 3 layers (edges never cross graphs -> no grid
// sync needed; h carried in LDS, never touches HBM).
// (512,8): targets 4 blocks/CU (LDS 40448*4 = 161792 <= 163840).  R2 hit this
// occupancy but spilled ~149 MB/dispatch (old afr[4]-live GEMM); the ks-outer
// re-read structure drops the GEMM live set so 64 total regs should fit clean.
// Spill tripwire: WRITE_SIZE >> 2 MB means the cap failed again.
__global__ __launch_bounds__(512, 8) void gat3_kernel(
    const float* __restrict__ x,
    const unsigned short* __restrict__ wt0,
    const unsigned short* __restrict__ wt1,
    const unsigned short* __restrict__ wt2,
    const float* __restrict__ g0, const float* __restrict__ b0,
    const float* __restrict__ g1, const float* __restrict__ b1,
    const float* __restrict__ g2, const float* __restrict__ b2,
    const int* __restrict__ src, const int* __restrict__ dst,
    float* __restrict__ out)
{
    __shared__ unsigned short featT[HF * SP];   // 18432 B
    __shared__ unsigned short hbuf[NPG * HB];   // 13600 B (res/h/y carrier)
    __shared__ int cnt[NPG * CNTW];             // 3200 B, byte counts
    __shared__ float el_s[128], er_s[128];
    __shared__ int elmax_i[2];
    __shared__ float lnp[128], lnq[128];        // LN partials [head][row]
    __shared__ float psum4[4 * HF];             // readout partials [amt][col]
    __shared__ float gbL[2 * HF];               // current layer's [g|b]

    const int g = blockIdx.x, t = threadIdx.x;
    const int nbase = g * NPG;
    const int w = t >> 6, lane = t & 63, quad = lane >> 4, l16 = lane & 15;

    // independent global loads at cycle 0
    int es = 0, ed = 0;
    if (t < EPG) { es = src[g * EPG + t] - nbase; ed = dst[g * EPG + t] - nbase; }

    // L0 A-fragments from global fp32 x (early issue)
    const int mt = w & 3;
    int mrow = mt * 16 + l16;
    if (mrow >= NPG) mrow = NPG - 1;
    bf16x8 afr0[2];
    {
        const float* hrow = x + (size_t)(nbase + mrow) * 64;
#pragma unroll
        for (int ks = 0; ks < 2; ++ks) {
            int k0 = ks * 32 + quad * 8;
            float4 p0 = *(const float4*)(hrow + k0);
            float4 p1 = *(const float4*)(hrow + k0 + 4);
            unsigned au[4] = {f2bfpk(p0.x, p0.y), f2bfpk(p0.z, p0.w),
                              f2bfpk(p1.x, p1.y), f2bfpk(p1.z, p1.w)};
            __builtin_memcpy(&afr0[ks], au, 16);
        }
    }

    // init
    for (int i = t; i < NPG * CNTW; i += 512) cnt[i] = 0;
    if (t < 2) elmax_i[t] = (int)0x80000000;
    __syncthreads();

    // edge counts (byte-packed, 4/int), once for all 3 layers.  Per-pair
    // multiplicity in this fixed random input is tiny (<<255).
    if (t < EPG) atomicAdd(&cnt[ed * CNTW + (es >> 2)], 1 << ((es & 3) * 8));
    if (t < NPG) atomicAdd(&cnt[t * CNTW + (t >> 2)], 1 << ((t & 3) * 8));

    gat_layer<64, true>(afr0, wt0, g0, b0, out, 0, g, t,
                        featT, hbuf, cnt, el_s, er_s, elmax_i, lnp, lnq, psum4, gbL);
    gat_layer<128, false>(nullptr, wt1, g1, b1, out, 1, g, t,
                          featT, hbuf, cnt, el_s, er_s, elmax_i, lnp, lnq, psum4, gbL);
    gat_layer<128, false>(nullptr, wt2, g2, b2, out, 2, g, t,
                          featT, hbuf, cnt, el_s, er_s, elmax_i, lnp, lnq, psum4, gbL);
}

extern "C" void kernel_launch(void* const* d_in, const int* in_sizes, int n_in,
                              void* d_out, int out_size, void* d_ws, size_t ws_size,
                              hipStream_t stream) {
    const float* x   = (const float*)d_in[0];
    const float* W0  = (const float*)d_in[1];
    const float* al0 = (const float*)d_in[2];
    const float* ar0 = (const float*)d_in[3];
    const float* rW0 = (const float*)d_in[4];
    const float* g0  = (const float*)d_in[5];
    const float* b0  = (const float*)d_in[6];
    const float* W1  = (const float*)d_in[7];
    const float* al1 = (const float*)d_in[8];
    const float* ar1 = (const float*)d_in[9];
    const float* g1  = (const float*)d_in[10];
    const float* b1  = (const float*)d_in[11];
    const float* W2  = (const float*)d_in[12];
    const float* al2 = (const float*)d_in[13];
    const float* ar2 = (const float*)d_in[14];
    const float* g2  = (const float*)d_in[15];
    const float* b2  = (const float*)d_in[16];
    const int* src   = (const int*)d_in[17];
    const int* dst   = (const int*)d_in[18];
    float* out = (float*)d_out;

    unsigned short* wt0 = (unsigned short*)d_ws;            // 272 x 64
    unsigned short* wt1 = wt0 + 272 * 64;                   // 144 x 128
    unsigned short* wt2 = wt1 + 144 * 128;                  // 144 x 128

    prep_w<<<84, 256, 0, stream>>>(W0, rW0, W1, W2, al0, ar0, al1, ar1, al2, ar2,
                                   wt0, wt1, wt2);
    gat3_kernel<<<NGRAPH, 512, 0, stream>>>(
        x, wt0, wt1, wt2, g0, b0, g1, b1, g2, b2, src, dst, out);
}

// Round 5
// 235.146 us; speedup vs baseline: 1.0097x; 1.0097x over previous
//
#include <hip/hip_runtime.h>

#define NPG    50
#define HF     128
#define FDIM   64
#define NGRAPH 2048
#define EPG    400
#define SP     72     // featT row stride (bf16), 16B-aligned rows, bank-skewed
#define HB     136    // hbuf row stride (bf16), 16B-aligned rows
#define CNTW   16     // cnt row stride in ints (64 byte-counts per row)

typedef __attribute__((ext_vector_type(8))) short bf16x8;
typedef __attribute__((ext_vector_type(4))) float floatx4;
typedef __bf16 bfv2 __attribute__((ext_vector_type(2)));

__device__ __forceinline__ float leaky(float x, float s) { return x >= 0.f ? x : x * s; }

__device__ __forceinline__ unsigned short f2bf(float f) {
    __bf16 b = (__bf16)f;
    unsigned short u;
    __builtin_memcpy(&u, &b, 2);
    return u;
}
__device__ __forceinline__ unsigned f2bfpk(float a, float b) {
    bfv2 v;
    v[0] = (__bf16)a;
    v[1] = (__bf16)b;
    unsigned u;
    __builtin_memcpy(&u, &v, 4);
    return u;
}
__device__ __forceinline__ float bf2f(unsigned short h) {
    return __uint_as_float(((unsigned)h) << 16);
}
__device__ __forceinline__ int fkey(float f) { int b = __float_as_int(f); return b >= 0 ? b : b ^ 0x7fffffff; }
__device__ __forceinline__ float funkey(int k) { return __int_as_float(k >= 0 ? k : k ^ 0x7fffffff); }

// ---- DPP cross-lane (VALU pipe, ZERO LDS -- R4 showed the LDS pipe is the
// per-CU wall; __shfl_xor lowers to ds_bpermute which contends it). ----
template <int CTRL>
__device__ __forceinline__ float dpp_addx(float x) {
    int yi = __builtin_amdgcn_update_dpp(0, __float_as_int(x), CTRL, 0xf, 0xf, true);
    return x + __int_as_float(yi);
}
// sum over each 16-lane row: xor1, xor2, then half-mirror(^7 == ^4 once
// quad-uniform), mirror(^15 == ^8 once 8-uniform).  All lanes get the sum.
__device__ __forceinline__ float row16_sum(float x) {
    x = dpp_addx<0xB1>(x);    // quad_perm(1,0,3,2)
    x = dpp_addx<0x4E>(x);    // quad_perm(2,3,0,1)
    x = dpp_addx<0x141>(x);   // row_half_mirror
    x = dpp_addx<0x140>(x);   // row_mirror
    return x;
}

// sigma column permutation for hbuf storage (within each 64-col head):
//   store position p = (c&15)*4 + ((c>>4)&3)   (c = true col within head)
//   inverse        c = (p&3)*16 + (p>>2)
// Makes the epilogue's per-thread 4 cols {nt*16+l16} CONTIGUOUS in LDS
// (b64 read/write instead of 4x scalar u16).  wt1/wt2 k-rows are permuted
// identically in prep_w so the next layer's A-frag reads (storage order)
// contract against matching weight rows.  x-features (layer 0 k) unpermuted.

__global__ void prep_w(const float* __restrict__ W0, const float* __restrict__ rW0,
                       const float* __restrict__ W1, const float* __restrict__ W2,
                       const float* __restrict__ al0, const float* __restrict__ ar0,
                       const float* __restrict__ al1, const float* __restrict__ ar1,
                       const float* __restrict__ al2, const float* __restrict__ ar2,
                       unsigned short* __restrict__ wt0, unsigned short* __restrict__ wt1,
                       unsigned short* __restrict__ wt2) {
    if (blockIdx.x >= 64) {
        int gid = (blockIdx.x - 64) * 256 + threadIdx.x;   // [0, 5120)
        if (gid < 1024) {            // layer 0 attn tile: k = true x-features
            int la = gid >> 6, k = gid & 63;
            unsigned short o = 0;
            if (la < 8) {
                const float* a = (la < 4) ? al0 : ar0;
                int h = (la >> 1) & 1;
                float v = 0.f;
                for (int f = 0; f < 64; ++f) v += W0[k * 128 + h * 64 + f] * a[h * 64 + f];
                __bf16 hi = (__bf16)v;
                if (la & 1) o = f2bf(v - (float)hi);
                else __builtin_memcpy(&o, &hi, 2);
            }
            wt0[(256 + la) * 64 + k] = o;
        } else {                     // layers 1/2 attn tiles: k sigma-permuted
            int q = gid - 1024;
            int l = q >> 11;
            int la = (q >> 7) & 15, kp = q & 127;
            int ktrue = (kp & 64) + ((kp & 3) * 16) + ((kp & 63) >> 2);
            const float* W = l ? W2 : W1;
            unsigned short o = 0;
            if (la < 8) {
                const float* a = l ? ((la < 4) ? al2 : ar2) : ((la < 4) ? al1 : ar1);
                int h = (la >> 1) & 1;
                float v = 0.f;
                for (int f = 0; f < 64; ++f) v += W[ktrue * 128 + h * 64 + f] * a[h * 64 + f];
                __bf16 hi = (__bf16)v;
                if (la & 1) o = f2bf(v - (float)hi);
                else __builtin_memcpy(&o, &hi, 2);
            }
            (l ? wt2 : wt1)[(128 + la) * 128 + kp] = o;
        }
        return;
    }
    int i = blockIdx.x * 256 + threadIdx.x;
    if (i < 256 * 64) {              // wt0 main: k = true x-features
        int n = i >> 6, k = i & 63;
        float v = (n < 128) ? W0[k * 128 + n] : rW0[k * 128 + (n - 128)];
        wt0[i] = f2bf(v);
    }
    if (i < 128 * 128) {             // wt1/wt2 main: k sigma-permuted
        int n = i >> 7, kp = i & 127;
        int ktrue = (kp & 64) + ((kp & 3) * 16) + ((kp & 63) >> 2);
        wt1[i] = f2bf(W1[ktrue * 128 + n]);
        wt2[i] = f2bf(W2[ktrue * 128 + n]);
    }
}

// One GAT layer, fully in-block.  hbuf (sigma-ordered cols) holds
// (RESW: x@resW0, else: input h) on entry to the epilogue, this layer's y on
// exit.  NO float atomics: uniquely-owned LDS slots + fixed-order sums ->
// bit-deterministic.
template <int K, bool RESW>
__device__ __forceinline__ void gat_layer(
    const bf16x8* afr_in,                       // RESW: preloaded A-frags
    const unsigned short* __restrict__ Wt,
    const float* __restrict__ gp, const float* __restrict__ bp,
    float* __restrict__ out, int layer, int g, int t,
    unsigned short* featT, unsigned short* hbuf, int* cnt,
    float* el_s, float* er_s, int* elmax_i,
    float* lnp, float* lnq, float* psum4, float* gbL)
{
    const int w = t >> 6, lane = t & 63, quad = lane >> 4, l16 = lane & 15;
    constexpr int KS = K / 32;
    constexpr int ATTN_ROW = RESW ? 256 : 128;  // attn tile base row in Wt
    const int mt = w & 3;
    int mrow = mt * 16 + l16;
    if (mrow >= NPG) mrow = NPG - 1;
    const floatx4 zf = {0.f, 0.f, 0.f, 0.f};

    // per-layer g|b reload, stored in sigma-order so the epilogue reads
    // contiguous float4.  Written before B1, read after B2 -> ordered.
    if (t < HF) {
        int p = (t & 64) + ((t & 15) * 4) + ((t >> 4) & 3);
        gbL[p] = gp[t];
        gbL[HF + p] = bp[t];
    }

    // ---- A-fragments (registers; 4 b128 LDS reads total for K=128) ----
    bf16x8 afr[KS];
    if constexpr (RESW) {
#pragma unroll
        for (int ks = 0; ks < KS; ++ks) afr[ks] = afr_in[ks];
    } else {
#pragma unroll
        for (int ks = 0; ks < KS; ++ks)
            afr[ks] = *(const bf16x8*)&hbuf[mrow * HB + ks * 32 + quad * 8];
    }

    // ---- main GEMM via MFMA + featT/res stores ----
    if constexpr (RESW) {
        // two SEQUENTIAL passes of 4 N-tiles: peak acc = 16 AGPRs.
        // unroll 1 is load-bearing -- full unroll re-fuses to 32 AGPRs.
#pragma unroll 1
        for (int half = 0; half < 2; ++half) {
            const int nb = (w >> 2) * 8 + half * 4;
            floatx4 acc[4];
#pragma unroll
            for (int nt = 0; nt < 4; ++nt) acc[nt] = zf;
#pragma unroll
            for (int nt = 0; nt < 4; ++nt) {
                const unsigned short* wrow = Wt + (size_t)((nb + nt) * 16 + l16) * K;
#pragma unroll
                for (int ks = 0; ks < KS; ++ks) {
                    bf16x8 b = *(const bf16x8*)(wrow + ks * 32 + quad * 8);
                    acc[nt] = __builtin_amdgcn_mfma_f32_16x16x32_bf16(afr[ks], b, acc[nt], 0, 0, 0);
                }
            }
#pragma unroll
            for (int nt = 0; nt < 4; ++nt) {
                int n = (nb + nt) * 16 + l16;
                if (n < HF) {
                    uint2 pk = {f2bfpk(acc[nt][0], acc[nt][1]),
                                f2bfpk(acc[nt][2], acc[nt][3])};
                    *(uint2*)&featT[n * SP + mt * 16 + quad * 4] = pk;
                } else {
                    int c = n - HF;                       // residual -> sigma pos
                    int spos = (c & 64) + ((c & 15) * 4) + ((c >> 4) & 3);
#pragma unroll
                    for (int r = 0; r < 4; ++r) {
                        int dr = mt * 16 + quad * 4 + r;
                        if (dr < NPG) hbuf[dr * HB + spos] = f2bf(acc[nt][r]);
                    }
                }
            }
        }
    } else {
        const int ntbase = (w >> 2) * 4;
        floatx4 acc[4];
#pragma unroll
        for (int nt = 0; nt < 4; ++nt) acc[nt] = zf;
#pragma unroll
        for (int nt = 0; nt < 4; ++nt) {
            const unsigned short* wrow = Wt + (size_t)((ntbase + nt) * 16 + l16) * K;
#pragma unroll
            for (int ks = 0; ks < KS; ++ks) {
                bf16x8 b = *(const bf16x8*)(wrow + ks * 32 + quad * 8);
                acc[nt] = __builtin_amdgcn_mfma_f32_16x16x32_bf16(afr[ks], b, acc[nt], 0, 0, 0);
            }
        }
#pragma unroll
        for (int nt = 0; nt < 4; ++nt) {
            int n = (ntbase + nt) * 16 + l16;
            uint2 pk = {f2bfpk(acc[nt][0], acc[nt][1]),
                        f2bfpk(acc[nt][2], acc[nt][3])};
            *(uint2*)&featT[n * SP + mt * 16 + quad * 4] = pk;
        }
    }

    // ---- el/er via the appended attn N-tile; hi+lo merged with DPP xor1 ----
    if (w < 4) {
        floatx4 ae = zf;
        const unsigned short* wrow = Wt + (size_t)(ATTN_ROW + l16) * K;
#pragma unroll
        for (int ks = 0; ks < KS; ++ks) {
            bf16x8 b = *(const bf16x8*)(wrow + ks * 32 + quad * 8);
            ae = __builtin_amdgcn_mfma_f32_16x16x32_bf16(afr[ks], b, ae, 0, 0, 0);
        }
#pragma unroll
        for (int r = 0; r < 4; ++r) {
            float v = dpp_addx<0xB1>(ae[r]);              // hi + lo (xor1, VALU)
            if ((l16 & 1) == 0 && l16 < 8) {
                int row = mt * 16 + quad * 4 + r;
                int hd2 = (l16 >> 1) & 1;
                if (l16 < 4) {
                    el_s[hd2 * 64 + row] = v;
                    atomicMax(&elmax_i[hd2], fkey(v));    // int max: exact
                } else {
                    er_s[hd2 * 64 + row] = v;
                }
            }
        }
    }
    __syncthreads();   // B1

    // ---- exp A-frag + aggregation MFMA + epilogue ----
    const int hd = w >> 2, amt = w & 3;
    const int d = amt * 16 + l16;    // A-frag dst row

    const float erd = er_s[hd * 64 + d];
    const float md = leaky(funkey(elmax_i[hd]) + erd, 0.2f);
    const int dcl = d < NPG ? d : NPG - 1;
    const int* crow = &cnt[dcl * CNTW];

    bf16x8 ap[2];
    float rowsum = 0.f;
#pragma unroll
    for (int ks = 0; ks < 2; ++ks) {
        float4 ev0 = *(const float4*)&el_s[hd * 64 + ks * 32 + quad * 8];
        float4 ev1 = *(const float4*)&el_s[hd * 64 + ks * 32 + quad * 8 + 4];
        const float ev[8] = {ev0.x, ev0.y, ev0.z, ev0.w, ev1.x, ev1.y, ev1.z, ev1.w};
        int2 cw = *(const int2*)&crow[ks * 8 + quad * 2];   // 8 byte-counts
        unsigned au[4];
#pragma unroll
        for (int jp = 0; jp < 4; ++jp) {
            float e0 = ev[2 * jp] + erd;
            float e1 = ev[2 * jp + 1] + erd;
            e0 = fmaxf(e0, 0.2f * e0);
            e1 = fmaxf(e1, 0.2f * e1);
            float p0 = __expf(e0 - md);
            float p1 = __expf(e1 - md);
            int w32 = (jp & 2) ? cw.y : cw.x;
            int sh = (jp & 1) * 16;
            int c0 = (w32 >> sh) & 0xff;
            int c1 = (w32 >> (sh + 8)) & 0xff;
            unsigned pk = f2bfpk((float)c0 * p0, (float)c1 * p1);  // c==0 -> exact 0
            au[jp] = pk;
            rowsum += __uint_as_float(pk << 16) + __uint_as_float(pk & 0xffff0000u);
        }
        __builtin_memcpy(&ap[ks], au, 16);
    }
    rowsum += __shfl_xor(rowsum, 16, 64);
    rowsum += __shfl_xor(rowsum, 32, 64);
    const float rden = 1.f / fmaxf(rowsum, 1e-30f);

    floatx4 ag[4];
#pragma unroll
    for (int nt = 0; nt < 4; ++nt) ag[nt] = zf;
#pragma unroll
    for (int nt = 0; nt < 4; ++nt) {
        const unsigned short* fr = &featT[(hd * 64 + nt * 16 + l16) * SP];
#pragma unroll
        for (int ks = 0; ks < 2; ++ks) {
            bf16x8 b = *(const bf16x8*)(fr + ks * 32 + quad * 8);
            ag[nt] = __builtin_amdgcn_mfma_f32_16x16x32_bf16(ap[ks], b, ag[nt], 0, 0, 0);
        }
    }

    // rden for accumulator row quad*4+r lives at lane l16'=quad*4+r of the
    // 16-group (group-dependent source -> stays bpermute, 4 ops).
    float rdvs[4] = {__shfl(rden, quad * 4 + 0, 16), __shfl(rden, quad * 4 + 1, 16),
                     __shfl(rden, quad * 4 + 2, 16), __shfl(rden, quad * 4 + 3, 16)};

    // scale + residual (sigma-packed b64 read); LN partials via DPP row-sum
    float s1[4] = {0, 0, 0, 0}, s2[4] = {0, 0, 0, 0};
#pragma unroll
    for (int r = 0; r < 4; ++r) {
        int dd = amt * 16 + quad * 4 + r;
        int dc = dd < NPG ? dd : NPG - 1;
        uint2 rv = *(const uint2*)&hbuf[dc * HB + hd * 64 + l16 * 4];
        float res[4] = {bf2f((unsigned short)(rv.x & 0xffffu)),
                        bf2f((unsigned short)(rv.x >> 16)),
                        bf2f((unsigned short)(rv.y & 0xffffu)),
                        bf2f((unsigned short)(rv.y >> 16))};
        float rdv = rdvs[r];
#pragma unroll
        for (int nt = 0; nt < 4; ++nt) {
            float vv = fmaf(ag[nt][r], rdv, res[nt]);
            ag[nt][r] = vv;
            s1[r] += vv;
            s2[r] = fmaf(vv, vv, s2[r]);
        }
    }
#pragma unroll
    for (int r = 0; r < 4; ++r) {
        s1[r] = row16_sum(s1[r]);     // DPP: VALU pipe, zero LDS
        s2[r] = row16_sum(s2[r]);
    }
    if (l16 == 0) {
#pragma unroll
        for (int r = 0; r < 4; ++r) {
            int dd = amt * 16 + quad * 4 + r;   // slot [hd][dd]: single writer
            lnp[hd * 64 + dd] = s1[r];
            lnq[hd * 64 + dd] = s2[r];
        }
    }
    __syncthreads();   // B2: LN slots written; hbuf/featT reads done

    // re-arm elmax for the next layer (reads finished at B2, writes after B3)
    if (t < 2) elmax_i[t] = (int)0x80000000;

    // vectorized epilogue parameter loads (sigma-contiguous)
    float4 ga  = *(const float4*)&gbL[hd * 64 + l16 * 4];
    float4 ba  = *(const float4*)&gbL[HF + hd * 64 + l16 * 4];
    float4 lp0 = *(const float4*)&lnp[amt * 16 + quad * 4];
    float4 lp1 = *(const float4*)&lnp[64 + amt * 16 + quad * 4];
    float4 lq0 = *(const float4*)&lnq[amt * 16 + quad * 4];
    float4 lq1 = *(const float4*)&lnq[64 + amt * 16 + quad * 4];

    float part[4] = {0, 0, 0, 0};
#pragma unroll
    for (int r = 0; r < 4; ++r) {
        int dd = amt * 16 + quad * 4 + r;
        if (dd < NPG) {
            float mu = (lp0[r] + lp1[r]) * (1.f / HF);
            float rs = rsqrtf((lq0[r] + lq1[r]) * (1.f / HF) - mu * mu + 1e-5f);
            float y4[4];
#pragma unroll
            for (int nt = 0; nt < 4; ++nt) {
                float y = (ag[nt][r] - mu) * rs * ga[nt] + ba[nt];
                y = leaky(y, 0.1f);
                y4[nt] = y;
                part[nt] += y;
            }
            uint2 pk = {f2bfpk(y4[0], y4[1]), f2bfpk(y4[2], y4[3])};
            *(uint2*)&hbuf[dd * HB + hd * 64 + l16 * 4] = pk;   // sigma-packed
        }
    }
#pragma unroll
    for (int nt = 0; nt < 4; ++nt) {
        part[nt] += __shfl_xor(part[nt], 16, 64);
        part[nt] += __shfl_xor(part[nt], 32, 64);
    }
    if (quad == 0) {
#pragma unroll
        for (int nt = 0; nt < 4; ++nt)
            psum4[amt * HF + hd * 64 + nt * 16 + l16] = part[nt];  // TRUE col idx
    }
    __syncthreads();   // B3: y visible (next layer A-frags), psum4 complete

    if (t < FDIM) {
        float s = 0.f;
#pragma unroll
        for (int a4 = 0; a4 < 4; ++a4)                   // fixed summation order
            s += psum4[a4 * HF + t] + psum4[a4 * HF + t + FDIM];
        out[(size_t)g * (3 * FDIM) + layer * FDIM + t] = leaky(s * (1.f / (2 * NPG)), 0.1f);
    }
}

// One block per graph runs all 3 layers.  (512,6): R2/R3/R4 proved time is
// INSENSITIVE to occupancy above ~2.5 blocks/CU (LDS pipe is the per-CU wall)
// -> pick the proven no-spill config.  Spill tripwire: WRITE_SIZE >> 2 MB.
__global__ __launch_bounds__(512, 6) void gat3_kernel(
    const float* __restrict__ x,
    const unsigned short* __restrict__ wt0,
    const unsigned short* __restrict__ wt1,
    const unsigned short* __restrict__ wt2,
    const float* __restrict__ g0, const float* __restrict__ b0,
    const float* __restrict__ g1, const float* __restrict__ b1,
    const float* __restrict__ g2, const float* __restrict__ b2,
    const int* __restrict__ src, const int* __restrict__ dst,
    float* __restrict__ out)
{
    __shared__ unsigned short featT[HF * SP];   // 18432 B
    __shared__ unsigned short hbuf[NPG * HB];   // 13600 B (res/h/y, sigma cols)
    __shared__ int cnt[NPG * CNTW];             // 3200 B, byte counts
    __shared__ float el_s[128], er_s[128];
    __shared__ int elmax_i[2];
    __shared__ float lnp[128], lnq[128];        // LN partials [head][row]
    __shared__ float psum4[4 * HF];             // readout partials [amt][col]
    __shared__ float gbL[2 * HF];               // current layer's [g|b], sigma

    const int g = blockIdx.x, t = threadIdx.x;
    const int nbase = g * NPG;
    const int w = t >> 6, lane = t & 63, quad = lane >> 4, l16 = lane & 15;

    // independent global loads at cycle 0
    int es = 0, ed = 0;
    if (t < EPG) { es = src[g * EPG + t] - nbase; ed = dst[g * EPG + t] - nbase; }

    // L0 A-fragments from global fp32 x (early issue); x-features unpermuted
    const int mt = w & 3;
    int mrow = mt * 16 + l16;
    if (mrow >= NPG) mrow = NPG - 1;
    bf16x8 afr0[2];
    {
        const float* hrow = x + (size_t)(nbase + mrow) * 64;
#pragma unroll
        for (int ks = 0; ks < 2; ++ks) {
            int k0 = ks * 32 + quad * 8;
            float4 p0 = *(const float4*)(hrow + k0);
            float4 p1 = *(const float4*)(hrow + k0 + 4);
            unsigned au[4] = {f2bfpk(p0.x, p0.y), f2bfpk(p0.z, p0.w),
                              f2bfpk(p1.x, p1.y), f2bfpk(p1.z, p1.w)};
            __builtin_memcpy(&afr0[ks], au, 16);
        }
    }

    // init
    for (int i = t; i < NPG * CNTW; i += 512) cnt[i] = 0;
    if (t < 2) elmax_i[t] = (int)0x80000000;
    __syncthreads();

    // edge counts (byte-packed, 4/int), once for all 3 layers.
    if (t < EPG) atomicAdd(&cnt[ed * CNTW + (es >> 2)], 1 << ((es & 3) * 8));
    if (t < NPG) atomicAdd(&cnt[t * CNTW + (t >> 2)], 1 << ((t & 3) * 8));

    gat_layer<64, true>(afr0, wt0, g0, b0, out, 0, g, t,
                        featT, hbuf, cnt, el_s, er_s, elmax_i, lnp, lnq, psum4, gbL);
    gat_layer<128, false>(nullptr, wt1, g1, b1, out, 1, g, t,
                          featT, hbuf, cnt, el_s, er_s, elmax_i, lnp, lnq, psum4, gbL);
    gat_layer<128, false>(nullptr, wt2, g2, b2, out, 2, g, t,
                          featT, hbuf, cnt, el_s, er_s, elmax_i, lnp, lnq, psum4, gbL);
}

extern "C" void kernel_launch(void* const* d_in, const int* in_sizes, int n_in,
                              void* d_out, int out_size, void* d_ws, size_t ws_size,
                              hipStream_t stream) {
    const float* x   = (const float*)d_in[0];
    const float* W0  = (const float*)d_in[1];
    const float* al0 = (const float*)d_in[2];
    const float* ar0 = (const float*)d_in[3];
    const float* rW0 = (const float*)d_in[4];
    const float* g0  = (const float*)d_in[5];
    const float* b0  = (const float*)d_in[6];
    const float* W1  = (const float*)d_in[7];
    const float* al1 = (const float*)d_in[8];
    const float* ar1 = (const float*)d_in[9];
    const float* g1  = (const float*)d_in[10];
    const float* b1  = (const float*)d_in[11];
    const float* W2  = (const float*)d_in[12];
    const float* al2 = (const float*)d_in[13];
    const float* ar2 = (const float*)d_in[14];
    const float* g2  = (const float*)d_in[15];
    const float* b2  = (const float*)d_in[16];
    const int* src   = (const int*)d_in[17];
    const int* dst   = (const int*)d_in[18];
    float* out = (float*)d_out;

    unsigned short* wt0 = (unsigned short*)d_ws;            // 272 x 64
    unsigned short* wt1 = wt0 + 272 * 64;                   // 144 x 128
    unsigned short* wt2 = wt1 + 144 * 128;                  // 144 x 128

    prep_w<<<84, 256, 0, stream>>>(W0, rW0, W1, W2, al0, ar0, al1, ar1, al2, ar2,
                                   wt0, wt1, wt2);
    gat3_kernel<<<NGRAPH, 512, 0, stream>>>(
        x, wt0, wt1, wt2, g0, b0, g1, b1, g2, b2, src, dst, out);
}

// Round 6
// 226.899 us; speedup vs baseline: 1.0464x; 1.0363x over previous
//
#include <hip/hip_runtime.h>

#define NPG    50
#define HF     128
#define FDIM   64
#define NGRAPH 2048
#define EPG    400
#define SP     72     // featT row stride (bf16), 16B-aligned rows, bank-skewed
#define HB     136    // hbuf row stride (bf16), 16B-aligned rows
#define CNTW   16     // cnt row stride in ints (64 byte-counts per row)

typedef __attribute__((ext_vector_type(8))) short bf16x8;
typedef __attribute__((ext_vector_type(4))) float floatx4;
typedef __bf16 bfv2 __attribute__((ext_vector_type(2)));

__device__ __forceinline__ float leaky(float x, float s) { return x >= 0.f ? x : x * s; }

__device__ __forceinline__ unsigned short f2bf(float f) {
    __bf16 b = (__bf16)f;
    unsigned short u;
    __builtin_memcpy(&u, &b, 2);
    return u;
}
__device__ __forceinline__ unsigned f2bfpk(float a, float b) {
    bfv2 v;
    v[0] = (__bf16)a;
    v[1] = (__bf16)b;
    unsigned u;
    __builtin_memcpy(&u, &v, 4);
    return u;
}
__device__ __forceinline__ float bf2f(unsigned short h) {
    return __uint_as_float(((unsigned)h) << 16);
}
__device__ __forceinline__ int fkey(float f) { int b = __float_as_int(f); return b >= 0 ? b : b ^ 0x7fffffff; }
__device__ __forceinline__ float funkey(int k) { return __int_as_float(k >= 0 ? k : k ^ 0x7fffffff); }

// ---- DPP cross-lane (VALU pipe, zero LDS) ----
template <int CTRL>
__device__ __forceinline__ float dpp_addx(float x) {
    int yi = __builtin_amdgcn_update_dpp(0, __float_as_int(x), CTRL, 0xf, 0xf, true);
    return x + __int_as_float(yi);
}
__device__ __forceinline__ float row16_sum(float x) {
    x = dpp_addx<0xB1>(x);    // quad_perm(1,0,3,2)
    x = dpp_addx<0x4E>(x);    // quad_perm(2,3,0,1)
    x = dpp_addx<0x141>(x);   // row_half_mirror
    x = dpp_addx<0x140>(x);   // row_mirror
    return x;
}

// sigma column permutation for hbuf storage (within each 64-col head):
//   store position p = (c&15)*4 + ((c>>4)&3);  inverse c = (p&3)*16 + (p>>2)
// Epilogue's per-thread 4 cols {nt*16+l16} are CONTIGUOUS in LDS (b64 ops).
// wt1/wt2 k-rows permuted identically in prep_w; layer-0 k (x feats) unpermuted.

__global__ void prep_w(const float* __restrict__ W0, const float* __restrict__ rW0,
                       const float* __restrict__ W1, const float* __restrict__ W2,
                       const float* __restrict__ al0, const float* __restrict__ ar0,
                       const float* __restrict__ al1, const float* __restrict__ ar1,
                       const float* __restrict__ al2, const float* __restrict__ ar2,
                       unsigned short* __restrict__ wt0, unsigned short* __restrict__ wt1,
                       unsigned short* __restrict__ wt2) {
    if (blockIdx.x >= 64) {
        int gid = (blockIdx.x - 64) * 256 + threadIdx.x;   // [0, 5120)
        if (gid < 1024) {            // layer 0 attn tile: k = true x-features
            int la = gid >> 6, k = gid & 63;
            unsigned short o = 0;
            if (la < 8) {
                const float* a = (la < 4) ? al0 : ar0;
                int h = (la >> 1) & 1;
                float v = 0.f;
                for (int f = 0; f < 64; ++f) v += W0[k * 128 + h * 64 + f] * a[h * 64 + f];
                __bf16 hi = (__bf16)v;
                if (la & 1) o = f2bf(v - (float)hi);
                else __builtin_memcpy(&o, &hi, 2);
            }
            wt0[(256 + la) * 64 + k] = o;
        } else {                     // layers 1/2 attn tiles: k sigma-permuted
            int q = gid - 1024;
            int l = q >> 11;
            int la = (q >> 7) & 15, kp = q & 127;
            int ktrue = (kp & 64) + ((kp & 3) * 16) + ((kp & 63) >> 2);
            const float* W = l ? W2 : W1;
            unsigned short o = 0;
            if (la < 8) {
                const float* a = l ? ((la < 4) ? al2 : ar2) : ((la < 4) ? al1 : ar1);
                int h = (la >> 1) & 1;
                float v = 0.f;
                for (int f = 0; f < 64; ++f) v += W[ktrue * 128 + h * 64 + f] * a[h * 64 + f];
                __bf16 hi = (__bf16)v;
                if (la & 1) o = f2bf(v - (float)hi);
                else __builtin_memcpy(&o, &hi, 2);
            }
            (l ? wt2 : wt1)[(128 + la) * 128 + kp] = o;
        }
        return;
    }
    int i = blockIdx.x * 256 + threadIdx.x;
    if (i < 256 * 64) {              // wt0 main: k = true x-features
        int n = i >> 6, k = i & 63;
        float v = (n < 128) ? W0[k * 128 + n] : rW0[k * 128 + (n - 128)];
        wt0[i] = f2bf(v);
    }
    if (i < 128 * 128) {             // wt1/wt2 main: k sigma-permuted
        int n = i >> 7, kp = i & 127;
        int ktrue = (kp & 64) + ((kp & 3) * 16) + ((kp & 63) >> 2);
        wt1[i] = f2bf(W1[ktrue * 128 + n]);
        wt2[i] = f2bf(W2[ktrue * 128 + n]);
    }
}

// One GAT layer, fully in-block.  hbuf (sigma-ordered cols) holds
// (RESW: x@resW0, else: input h) on entry to the epilogue, this layer's y on
// exit.  NO float atomics: uniquely-owned LDS slots + fixed-order sums ->
// bit-deterministic.
// R6 register discipline (third 64-reg attempt; R2/R4 spilled): no hoisted
// arrays anywhere -- epilogue params read scalar per row, rden shuffled
// inline, L0 A-frags loaded inside the layer, one floatx4[4] accumulator bank
// live at a time (acc -> ae -> ag reuse).  Target 48 VGPR + 16 AGPR <= 64.
template <int K, bool RESW>
__device__ __forceinline__ void gat_layer(
    const float* __restrict__ xrow,             // RESW: this graph's x base
    const unsigned short* __restrict__ Wt,
    const float* __restrict__ gp, const float* __restrict__ bp,
    float* __restrict__ out, int layer, int g, int t,
    unsigned short* featT, unsigned short* hbuf, int* cnt,
    float* el_s, float* er_s, int* elmax_i,
    float* lnp, float* lnq, float* psum4, float* gbL)
{
    const int w = t >> 6, lane = t & 63, quad = lane >> 4, l16 = lane & 15;
    constexpr int KS = K / 32;
    constexpr int ATTN_ROW = RESW ? 256 : 128;  // attn tile base row in Wt
    const int mt = w & 3;
    int mrow = mt * 16 + l16;
    if (mrow >= NPG) mrow = NPG - 1;
    const floatx4 zf = {0.f, 0.f, 0.f, 0.f};

    // per-layer g|b reload, sigma-order.  Written before B1, read after B2.
    if (t < HF) {
        int p = (t & 64) + ((t & 15) * 4) + ((t >> 4) & 3);
        gbL[p] = gp[t];
        gbL[HF + p] = bp[t];
    }

    // ---- A-fragments (loaded HERE, not held across the prelude) ----
    bf16x8 afr[KS];
    if constexpr (RESW) {
        const float* hrow = xrow + (size_t)mrow * 64;
#pragma unroll
        for (int ks = 0; ks < KS; ++ks) {
            int k0 = ks * 32 + quad * 8;
            float4 p0 = *(const float4*)(hrow + k0);
            float4 p1 = *(const float4*)(hrow + k0 + 4);
            unsigned au[4] = {f2bfpk(p0.x, p0.y), f2bfpk(p0.z, p0.w),
                              f2bfpk(p1.x, p1.y), f2bfpk(p1.z, p1.w)};
            __builtin_memcpy(&afr[ks], au, 16);
        }
    } else {
#pragma unroll
        for (int ks = 0; ks < KS; ++ks)
            afr[ks] = *(const bf16x8*)&hbuf[mrow * HB + ks * 32 + quad * 8];
    }

    // ---- main GEMM via MFMA + featT/res stores ----
    if constexpr (RESW) {
        // two SEQUENTIAL passes of 4 N-tiles: peak acc = 16 AGPRs.
        // unroll 1 is load-bearing -- full unroll re-fuses to 32 AGPRs.
#pragma unroll 1
        for (int half = 0; half < 2; ++half) {
            const int nb = (w >> 2) * 8 + half * 4;
            floatx4 acc[4];
#pragma unroll
            for (int nt = 0; nt < 4; ++nt) acc[nt] = zf;
#pragma unroll
            for (int nt = 0; nt < 4; ++nt) {
                const unsigned short* wrow = Wt + (size_t)((nb + nt) * 16 + l16) * K;
#pragma unroll
                for (int ks = 0; ks < KS; ++ks) {
                    bf16x8 b = *(const bf16x8*)(wrow + ks * 32 + quad * 8);
                    acc[nt] = __builtin_amdgcn_mfma_f32_16x16x32_bf16(afr[ks], b, acc[nt], 0, 0, 0);
                }
            }
#pragma unroll
            for (int nt = 0; nt < 4; ++nt) {
                int n = (nb + nt) * 16 + l16;
                if (n < HF) {
                    uint2 pk = {f2bfpk(acc[nt][0], acc[nt][1]),
                                f2bfpk(acc[nt][2], acc[nt][3])};
                    *(uint2*)&featT[n * SP + mt * 16 + quad * 4] = pk;
                } else {
                    int c = n - HF;                       // residual -> sigma pos
                    int spos = (c & 64) + ((c & 15) * 4) + ((c >> 4) & 3);
#pragma unroll
                    for (int r = 0; r < 4; ++r) {
                        int dr = mt * 16 + quad * 4 + r;
                        if (dr < NPG) hbuf[dr * HB + spos] = f2bf(acc[nt][r]);
                    }
                }
            }
        }
    } else {
        const int ntbase = (w >> 2) * 4;
        floatx4 acc[4];
#pragma unroll
        for (int nt = 0; nt < 4; ++nt) acc[nt] = zf;
#pragma unroll
        for (int nt = 0; nt < 4; ++nt) {
            const unsigned short* wrow = Wt + (size_t)((ntbase + nt) * 16 + l16) * K;
#pragma unroll
            for (int ks = 0; ks < KS; ++ks) {
                bf16x8 b = *(const bf16x8*)(wrow + ks * 32 + quad * 8);
                acc[nt] = __builtin_amdgcn_mfma_f32_16x16x32_bf16(afr[ks], b, acc[nt], 0, 0, 0);
            }
        }
#pragma unroll
        for (int nt = 0; nt < 4; ++nt) {
            int n = (ntbase + nt) * 16 + l16;
            uint2 pk = {f2bfpk(acc[nt][0], acc[nt][1]),
                        f2bfpk(acc[nt][2], acc[nt][3])};
            *(uint2*)&featT[n * SP + mt * 16 + quad * 4] = pk;
        }
    }

    // ---- el/er via the appended attn N-tile; hi+lo merged with DPP xor1 ----
    if (w < 4) {
        floatx4 ae = zf;
        const unsigned short* wrow = Wt + (size_t)(ATTN_ROW + l16) * K;
#pragma unroll
        for (int ks = 0; ks < KS; ++ks) {
            bf16x8 b = *(const bf16x8*)(wrow + ks * 32 + quad * 8);
            ae = __builtin_amdgcn_mfma_f32_16x16x32_bf16(afr[ks], b, ae, 0, 0, 0);
        }
#pragma unroll
        for (int r = 0; r < 4; ++r) {
            float v = dpp_addx<0xB1>(ae[r]);              // hi + lo (xor1, VALU)
            if ((l16 & 1) == 0 && l16 < 8) {
                int row = mt * 16 + quad * 4 + r;
                int hd2 = (l16 >> 1) & 1;
                if (l16 < 4) {
                    el_s[hd2 * 64 + row] = v;
                    atomicMax(&elmax_i[hd2], fkey(v));    // int max: exact
                } else {
                    er_s[hd2 * 64 + row] = v;
                }
            }
        }
    }
    __syncthreads();   // B1

    // ---- exp A-frag + aggregation MFMA + epilogue ----
    const int hd = w >> 2, amt = w & 3;
    const int d = amt * 16 + l16;    // A-frag dst row

    const float erd = er_s[hd * 64 + d];
    const float md = leaky(funkey(elmax_i[hd]) + erd, 0.2f);
    const int dcl = d < NPG ? d : NPG - 1;
    const int* crow = &cnt[dcl * CNTW];

    bf16x8 ap[2];
    float rowsum = 0.f;
#pragma unroll
    for (int ks = 0; ks < 2; ++ks) {
        float4 ev0 = *(const float4*)&el_s[hd * 64 + ks * 32 + quad * 8];
        float4 ev1 = *(const float4*)&el_s[hd * 64 + ks * 32 + quad * 8 + 4];
        const float ev[8] = {ev0.x, ev0.y, ev0.z, ev0.w, ev1.x, ev1.y, ev1.z, ev1.w};
        int2 cw = *(const int2*)&crow[ks * 8 + quad * 2];   // 8 byte-counts
        unsigned au[4];
#pragma unroll
        for (int jp = 0; jp < 4; ++jp) {
            float e0 = ev[2 * jp] + erd;
            float e1 = ev[2 * jp + 1] + erd;
            e0 = fmaxf(e0, 0.2f * e0);
            e1 = fmaxf(e1, 0.2f * e1);
            float p0 = __expf(e0 - md);
            float p1 = __expf(e1 - md);
            int w32 = (jp & 2) ? cw.y : cw.x;
            int sh = (jp & 1) * 16;
            int c0 = (w32 >> sh) & 0xff;
            int c1 = (w32 >> (sh + 8)) & 0xff;
            unsigned pk = f2bfpk((float)c0 * p0, (float)c1 * p1);  // c==0 -> exact 0
            au[jp] = pk;
            rowsum += __uint_as_float(pk << 16) + __uint_as_float(pk & 0xffff0000u);
        }
        __builtin_memcpy(&ap[ks], au, 16);
    }
    rowsum += __shfl_xor(rowsum, 16, 64);
    rowsum += __shfl_xor(rowsum, 32, 64);
    const float rden = 1.f / fmaxf(rowsum, 1e-30f);

    floatx4 ag[4];
#pragma unroll
    for (int nt = 0; nt < 4; ++nt) ag[nt] = zf;
#pragma unroll
    for (int nt = 0; nt < 4; ++nt) {
        const unsigned short* fr = &featT[(hd * 64 + nt * 16 + l16) * SP];
#pragma unroll
        for (int ks = 0; ks < 2; ++ks) {
            bf16x8 b = *(const bf16x8*)(fr + ks * 32 + quad * 8);
            ag[nt] = __builtin_amdgcn_mfma_f32_16x16x32_bf16(ap[ks], b, ag[nt], 0, 0, 0);
        }
    }

    // scale + residual (sigma-packed b64 read); LN partials via DPP row-sum.
    // rden for row quad*4+r shuffled INLINE (no hoisted array -- reg diet).
    float s1[4] = {0, 0, 0, 0}, s2[4] = {0, 0, 0, 0};
#pragma unroll
    for (int r = 0; r < 4; ++r) {
        int dd = amt * 16 + quad * 4 + r;
        int dc = dd < NPG ? dd : NPG - 1;
        float rdv = __shfl(rden, quad * 4 + r, 16);
        uint2 rv = *(const uint2*)&hbuf[dc * HB + hd * 64 + l16 * 4];
#pragma unroll
        for (int nt = 0; nt < 4; ++nt) {
            unsigned hw = (nt & 1) ? ((nt & 2) ? rv.y >> 16 : rv.x >> 16)
                                   : ((nt & 2) ? rv.y & 0xffffu : rv.x & 0xffffu);
            float vv = fmaf(ag[nt][r], rdv, bf2f((unsigned short)hw));
            ag[nt][r] = vv;
            s1[r] += vv;
            s2[r] = fmaf(vv, vv, s2[r]);
        }
    }
#pragma unroll
    for (int r = 0; r < 4; ++r) {
        s1[r] = row16_sum(s1[r]);     // DPP: VALU pipe, zero LDS
        s2[r] = row16_sum(s2[r]);
    }
    if (l16 == 0) {
#pragma unroll
        for (int r = 0; r < 4; ++r) {
            int dd = amt * 16 + quad * 4 + r;   // slot [hd][dd]: single writer
            lnp[hd * 64 + dd] = s1[r];
            lnq[hd * 64 + dd] = s2[r];
        }
    }
    __syncthreads();   // B2: LN slots written; hbuf/featT reads done

    // re-arm elmax for the next layer (reads finished at B2, writes after B3)
    if (t < 2) elmax_i[t] = (int)0x80000000;

    // epilogue: scalar lnp/lnq reads per row (reg diet); g/b as one float4 pair
    float4 ga = *(const float4*)&gbL[hd * 64 + l16 * 4];
    float4 ba = *(const float4*)&gbL[HF + hd * 64 + l16 * 4];

    float part[4] = {0, 0, 0, 0};
#pragma unroll
    for (int r = 0; r < 4; ++r) {
        int dd = amt * 16 + quad * 4 + r;
        if (dd < NPG) {
            float mu = (lnp[dd] + lnp[64 + dd]) * (1.f / HF);   // head0 + head1
            float rs = rsqrtf((lnq[dd] + lnq[64 + dd]) * (1.f / HF) - mu * mu + 1e-5f);
            float y4[4];
#pragma unroll
            for (int nt = 0; nt < 4; ++nt) {
                float y = (ag[nt][r] - mu) * rs * ga[nt] + ba[nt];
                y = leaky(y, 0.1f);
                y4[nt] = y;
                part[nt] += y;
            }
            uint2 pk = {f2bfpk(y4[0], y4[1]), f2bfpk(y4[2], y4[3])};
            *(uint2*)&hbuf[dd * HB + hd * 64 + l16 * 4] = pk;   // sigma-packed
        }
    }
#pragma unroll
    for (int nt = 0; nt < 4; ++nt) {
        part[nt] += __shfl_xor(part[nt], 16, 64);
        part[nt] += __shfl_xor(part[nt], 32, 64);
    }
    if (quad == 0) {
#pragma unroll
        for (int nt = 0; nt < 4; ++nt)
            psum4[amt * HF + hd * 64 + nt * 16 + l16] = part[nt];  // TRUE col idx
    }
    __syncthreads();   // B3: y visible (next layer A-frags), psum4 complete

    if (t < FDIM) {
        float s = 0.f;
#pragma unroll
        for (int a4 = 0; a4 < 4; ++a4)                   // fixed summation order
            s += psum4[a4 * HF + t] + psum4[a4 * HF + t + FDIM];
        out[(size_t)g * (3 * FDIM) + layer * FDIM + t] = leaky(s * (1.f / (2 * NPG)), 0.1f);
    }
}

// One block per graph runs all 3 layers.  (512,8): the per-graph layer
// pipeline is inherently serial (no cross-layer overlap possible), so
// cross-block concurrency is the ONLY latency-hiding mechanism; 4 blocks/CU
// is the HW ceiling (32 waves).  R2/R4 hit 4 blocks but spilled ~150 MB
// (canceling the gain); this build is register-dieted to fit 64 clean.
// Spill tripwire: WRITE_SIZE >> 6 MB => declare 64-reg infeasible.
__global__ __launch_bounds__(512, 8) void gat3_kernel(
    const float* __restrict__ x,
    const unsigned short* __restrict__ wt0,
    const unsigned short* __restrict__ wt1,
    const unsigned short* __restrict__ wt2,
    const float* __restrict__ g0, const float* __restrict__ b0,
    const float* __restrict__ g1, const float* __restrict__ b1,
    const float* __restrict__ g2, const float* __restrict__ b2,
    const int* __restrict__ src, const int* __restrict__ dst,
    float* __restrict__ out)
{
    __shared__ unsigned short featT[HF * SP];   // 18432 B
    __shared__ unsigned short hbuf[NPG * HB];   // 13600 B (res/h/y, sigma cols)
    __shared__ int cnt[NPG * CNTW];             // 3200 B, byte counts
    __shared__ float el_s[128], er_s[128];
    __shared__ int elmax_i[2];
    __shared__ float lnp[128], lnq[128];        // LN partials [head][row]
    __shared__ float psum4[4 * HF];             // readout partials [amt][col]
    __shared__ float gbL[2 * HF];               // current layer's [g|b], sigma

    const int g = blockIdx.x, t = threadIdx.x;
    const int nbase = g * NPG;

    // independent global loads at cycle 0
    int es = 0, ed = 0;
    if (t < EPG) { es = src[g * EPG + t] - nbase; ed = dst[g * EPG + t] - nbase; }

    // init
    for (int i = t; i < NPG * CNTW; i += 512) cnt[i] = 0;
    if (t < 2) elmax_i[t] = (int)0x80000000;
    __syncthreads();

    // edge counts (byte-packed, 4/int), once for all 3 layers.
    if (t < EPG) atomicAdd(&cnt[ed * CNTW + (es >> 2)], 1 << ((es & 3) * 8));
    if (t < NPG) atomicAdd(&cnt[t * CNTW + (t >> 2)], 1 << ((t & 3) * 8));

    const float* xrow = x + (size_t)nbase * 64;
    gat_layer<64, true>(xrow, wt0, g0, b0, out, 0, g, t,
                        featT, hbuf, cnt, el_s, er_s, elmax_i, lnp, lnq, psum4, gbL);
    gat_layer<128, false>(nullptr, wt1, g1, b1, out, 1, g, t,
                          featT, hbuf, cnt, el_s, er_s, elmax_i, lnp, lnq, psum4, gbL);
    gat_layer<128, false>(nullptr, wt2, g2, b2, out, 2, g, t,
                          featT, hbuf, cnt, el_s, er_s, elmax_i, lnp, lnq, psum4, gbL);
}

extern "C" void kernel_launch(void* const* d_in, const int* in_sizes, int n_in,
                              void* d_out, int out_size, void* d_ws, size_t ws_size,
                              hipStream_t stream) {
    const float* x   = (const float*)d_in[0];
    const float* W0  = (const float*)d_in[1];
    const float* al0 = (const float*)d_in[2];
    const float* ar0 = (const float*)d_in[3];
    const float* rW0 = (const float*)d_in[4];
    const float* g0  = (const float*)d_in[5];
    const float* b0  = (const float*)d_in[6];
    const float* W1  = (const float*)d_in[7];
    const float* al1 = (const float*)d_in[8];
    const float* ar1 = (const float*)d_in[9];
    const float* g1  = (const float*)d_in[10];
    const float* b1  = (const float*)d_in[11];
    const float* W2  = (const float*)d_in[12];
    const float* al2 = (const float*)d_in[13];
    const float* ar2 = (const float*)d_in[14];
    const float* g2  = (const float*)d_in[15];
    const float* b2  = (const float*)d_in[16];
    const int* src   = (const int*)d_in[17];
    const int* dst   = (const int*)d_in[18];
    float* out = (float*)d_out;

    unsigned short* wt0 = (unsigned short*)d_ws;            // 272 x 64
    unsigned short* wt1 = wt0 + 272 * 64;                   // 144 x 128
    unsigned short* wt2 = wt1 + 144 * 128;                  // 144 x 128

    prep_w<<<84, 256, 0, stream>>>(W0, rW0, W1, W2, al0, ar0, al1, ar1, al2, ar2,
                                   wt0, wt1, wt2);
    gat3_kernel<<<NGRAPH, 512, 0, stream>>>(
        x, wt0, wt1, wt2, g0, b0, g1, b1, g2, b2, src, dst, out);
}